// Round 16
// baseline (47.969 us; speedup 1.0000x reference)
//
#include <hip/hip_runtime.h>

// CTC batch cost, B=256 T=512 C=256 L=64 (S=129).
// R16: fwd and bwd chains in SEPARATE blocks (grid 512 = 2 x 256), each
// block = R13's proven 3-wave pipeline (1 DP consumer + 2 reg-staging
// producers, 8-row groups, 32 raw s_barrier rendezvous, 48-slot ring).
// 2-3 blocks/CU co-resident -> two INDEPENDENT sync domains per CU: one
// domain's barrier/restart bubbles are filled by the sibling's memory issue
// (R12: in-block sync overhead irremovable; R14: intra-block flag decoupling
// regressed; R15: requested-byte reduction null -> line delivery is the
// wall, bubbles are the residual). Cross-block combine: both blocks write
// 129-entry log2-domain vectors to d_ws, device-scope release fence +
// atomicAdd on per-b flag (zeroed each call via hipMemsetAsync); the SECOND
// finisher combines -- order-independent math, deterministic output.
// DP math: f64 linear domain, DPP shifts, log2 cut combine (absmax 0.0
// R6-R15).

constexpr int Bc = 256;
constexpr int Tc = 512;
constexpr int Cc = 256;
constexpr int Lc = 64;
constexpr int NS = 48;          // ring slots = 6 groups x 8 rows

#define EPSF (1e-7f)
#define NEGF (-1e30f)
#define WS_VEC_OFF 1024         // flags in ws[0..1023], vectors after
#define VSTRIDE 132

__device__ __forceinline__ float flog2(float x) {
    float r; asm("v_log_f32 %0, %1" : "=v"(r) : "v"(x)); return r;
}
__device__ __forceinline__ float fexp2(float x) {
    float r; asm("v_exp_f32 %0, %1" : "=v"(r) : "v"(x)); return r;
}
__device__ __forceinline__ float lse2(float a, float b) {
    float m = fmaxf(a, b);
    float d = fminf(a, b) - m;
    return m + flog2(1.f + fexp2(d));
}
// log2 of a positive double via exponent extraction + f32 mantissa log.
__device__ __forceinline__ float dlog2(double x) {
    if (!(x > 1e-300)) return NEGF;
    const int hb = __double2hiint(x);
    const int lb = __double2loint(x);
    const int e  = ((hb >> 20) & 0x7FF) - 1022;
    const double m = __hiloint2double((hb & 0x800FFFFF) | (1022 << 20), lb);
    return flog2((float)m) + (float)e;            // m in [0.5, 1)
}
__device__ __forceinline__ double dpp_up1_d(double old, double src) {   // lane i <- i-1
    const int rl = __builtin_amdgcn_update_dpp(
        __double2loint(old), __double2loint(src), 0x138, 0xF, 0xF, false);
    const int rh = __builtin_amdgcn_update_dpp(
        __double2hiint(old), __double2hiint(src), 0x138, 0xF, 0xF, false);
    return __hiloint2double(rh, rl);
}
__device__ __forceinline__ double dpp_dn1_d(double old, double src) {   // lane i <- i+1
    const int rl = __builtin_amdgcn_update_dpp(
        __double2loint(old), __double2loint(src), 0x130, 0xF, 0xF, false);
    const int rh = __builtin_amdgcn_update_dpp(
        __double2hiint(old), __double2hiint(src), 0x130, 0xF, 0xF, false);
    return __hiloint2double(rh, rl);
}

__global__ __launch_bounds__(192, 1) void ctc_half_kernel(
        const int* __restrict__ y_true,
        const float* __restrict__ y_pred,
        float* __restrict__ out,
        float* __restrict__ wsv,          // vectors: [(dir<<8)|b] * VSTRIDE
        int*   __restrict__ flags)        // per-b arrival counter (memset 0)
{
    const int bid  = blockIdx.x;
    const int b    = bid & 255;
    const int dir  = bid >> 8;            // 0 = fwd (t 0..255), 1 = bwd
    const int lane = threadIdx.x & 63;
    const int wid  = threadIdx.x >> 6;

    __shared__ float ring[NS][Cc];        // 48 KB

    const float* __restrict__ bbase = y_pred + (size_t)b * Tc * Cc;

    if (wid >= 1) {
        // ---------------- producer waves (R13 pipeline, half = wid-1) ------
        const int half = wid - 1;
        const float* __restrict__ g0 =
            dir ? (bbase + (size_t)(Tc - 1) * Cc + lane * 4)
                : (bbase + lane * 4);
        const ptrdiff_t stp = dir ? -(ptrdiff_t)Cc : (ptrdiff_t)Cc;

        float4 a0, a1, a2, a3, b0, b1, b2, b3;

#define GADDR(G, j) (g0 + stp * (8 * (G) + 4 * half + (j)))
#define LADDR(G, j) (&ring[((G) % 6) * 8 + 4 * half + (j)][lane * 4])
#define PLOAD(v0, v1, v2, v3, G)                                   \
        v0 = *(const float4*)GADDR(G, 0);                          \
        v1 = *(const float4*)GADDR(G, 1);                          \
        v2 = *(const float4*)GADDR(G, 2);                          \
        v3 = *(const float4*)GADDR(G, 3);
#define PWRITE(v0, v1, v2, v3, G)                                  \
        *(float4*)LADDR(G, 0) = v0;                                \
        *(float4*)LADDR(G, 1) = v1;                                \
        *(float4*)LADDR(G, 2) = v2;                                \
        *(float4*)LADDR(G, 3) = v3;

        PLOAD(a0, a1, a2, a3, 0)
        PLOAD(b0, b1, b2, b3, 1)
        asm volatile("s_waitcnt vmcnt(4)" ::: "memory");
        PWRITE(a0, a1, a2, a3, 0)
        asm volatile("s_waitcnt lgkmcnt(0)" ::: "memory");

        for (int g = 0; g < 32; g += 2) {
            asm volatile("" ::: "memory");
            __builtin_amdgcn_s_barrier();                  // #g
            asm volatile("" ::: "memory");
            if (g + 2 <= 31) { PLOAD(a0, a1, a2, a3, g + 2) }
            if (g <= 29) asm volatile("s_waitcnt vmcnt(4)" ::: "memory");
            else         asm volatile("s_waitcnt vmcnt(0)" ::: "memory");
            PWRITE(b0, b1, b2, b3, g + 1)
            asm volatile("s_waitcnt lgkmcnt(0)" ::: "memory");
            asm volatile("" ::: "memory");
            __builtin_amdgcn_s_barrier();                  // #g+1
            asm volatile("" ::: "memory");
            if (g + 3 <= 31) { PLOAD(b0, b1, b2, b3, g + 3) }
            if (g + 1 <= 29) asm volatile("s_waitcnt vmcnt(4)" ::: "memory");
            else             asm volatile("s_waitcnt vmcnt(0)" ::: "memory");
            if (g + 2 <= 31) {
                PWRITE(a0, a1, a2, a3, g + 2)
                asm volatile("s_waitcnt lgkmcnt(0)" ::: "memory");
            }
        }
#undef GADDR
#undef LADDR
#undef PLOAD
#undef PWRITE
        return;
    }

    // ---------------- consumer (DP) wave ----------------
    const int lab  = y_true[b * Lc + lane];
    const int labp = __shfl_up(lab, 1);
    const int labn = __shfl_down(lab, 1);

    double lo = 0.0, hi = 0.0, ex = 0.0;
    float v1, v2, v3;

    if (dir == 0) {
        const bool allowF = (lane >= 1) && (lab != labp);
        auto stepF = [&](float pBf, float pLf) {
            const double pB = (double)pBf, pL = (double)pLf;
            const double prevHi = dpp_up1_d(0.0, hi);
            const double sk  = allowF ? prevHi : 0.0;
            const double nlo = (lo + prevHi) * pB;
            const double nhi = (hi + lo + sk) * pL;
            ex = (ex + hi) * pB;     // real only at lane 63 (127->128)
            hi = nhi; lo = nlo;
        };
        int sb = 0;
        for (int g = 0; g < 32; ++g) {
            asm volatile("" ::: "memory");
            __builtin_amdgcn_s_barrier();        // group g ready
            asm volatile("" ::: "memory");
#define RDF(j) const float cL##j = ring[sb + j][lab] + EPSF, \
                           cB##j = ring[sb + j][Cc - 1] + EPSF;
            RDF(0) RDF(1) RDF(2) RDF(3) RDF(4) RDF(5) RDF(6) RDF(7)
#undef RDF
            if (g == 0) {
                lo = (lane == 0) ? (double)cB0 : 0.0;    // alpha0(0)
                hi = (lane == 0) ? (double)cL0 : 0.0;    // alpha0(1)
            } else stepF(cB0, cL0);
            stepF(cB1, cL1); stepF(cB2, cL2); stepF(cB3, cL3);
            stepF(cB4, cL4); stepF(cB5, cL5); stepF(cB6, cL6);
            stepF(cB7, cL7);
            sb += 8; if (sb >= NS) sb = 0;
        }
        v1 = dlog2(lo); v2 = dlog2(hi); v3 = dlog2(ex);   // alpha_255 logs
    } else {
        const bool allowB = (lane < 63) && (labn != lab);
        auto stepB = [&](float pBf, float pLf) {
            const double pB = (double)pBf, pL = (double)pLf;
            const double nlo_s = dpp_dn1_d(ex, lo);   // B(2l+2); l63 <- ex
            const double nhi_s = dpp_dn1_d(0.0, hi);  // B(2l+3); l63 <- 0
            const double sk = allowB ? nhi_s : 0.0;
            const double l2 = (lo + hi) * pB;
            const double h2 = (hi + nlo_s + sk) * pL;
            ex = ex * pB;
            lo = l2; hi = h2;
        };
        int sb = 0;
        for (int g = 0; g < 32; ++g) {
            asm volatile("" ::: "memory");
            __builtin_amdgcn_s_barrier();        // group g ready
            asm volatile("" ::: "memory");
#define RDB(j) const float cL##j = ring[sb + j][lab] + EPSF, \
                           cB##j = ring[sb + j][Cc - 1] + EPSF;
            RDB(0) RDB(1) RDB(2) RDB(3) RDB(4) RDB(5) RDB(6) RDB(7)
#undef RDB
            if (g == 0) {
                ex = (double)cB0;                          // beta511(128)
                hi = (lane == 63) ? (double)cL0 : 0.0;     // beta511(127)
                lo = 0.0;
            } else stepB(cB0, cL0);
            stepB(cB1, cL1); stepB(cB2, cL2); stepB(cB3, cL3);
            stepB(cB4, cL4); stepB(cB5, cL5); stepB(cB6, cL6);
            stepB(cB7, cL7);
            sb += 8; if (sb >= NS) sb = 0;
        }
        // cut combine half-step: C(s) = B(s) + B(s+1) + allowB(s)*B(s+2)
        const double nlo_s = dpp_dn1_d(ex, lo);
        const double nhi_s = dpp_dn1_d(0.0, hi);
        const double sk = allowB ? nhi_s : 0.0;
        v1 = dlog2(lo + hi);
        v2 = dlog2(hi + nlo_s + sk);
        v3 = dlog2(ex);
    }

    // publish this chain's vector, then combine if partner already done
    float* myv = wsv + (size_t)(((dir << 8) | b) * VSTRIDE);
    myv[lane]      = v1;
    myv[64 + lane] = v2;
    if (lane == 63) myv[128] = v3;
    __threadfence();                                  // device-scope release
    int old = 0;
    if (lane == 0) old = atomicAdd(&flags[b], 1);
    old = __shfl(old, 0);
    if (old == 1) {                                   // we are second: combine
        __threadfence();                              // acquire
        asm volatile("" ::: "memory");
        volatile const float* A = wsv + (size_t)(b * VSTRIDE);
        volatile const float* C = wsv + (size_t)((256 + b) * VSTRIDE);
        const float w1 = A[lane]      + C[lane];
        const float w2 = A[64 + lane] + C[64 + lane];
        float w = lse2(w1, w2);
        if (lane == 63) w = lse2(w, A[128] + C[128]);
        #pragma unroll
        for (int off = 32; off; off >>= 1) w = lse2(w, __shfl_xor(w, off));
        if (lane == 0)
            out[b] = -0.69314718055994530942f * w;    // ln2 * log2 -> ln
    }
}

extern "C" void kernel_launch(void* const* d_in, const int* in_sizes, int n_in,
                              void* d_out, int out_size, void* d_ws, size_t ws_size,
                              hipStream_t stream) {
    const int*   y_true = (const int*)d_in[0];
    const float* y_pred = (const float*)d_in[1];
    float*       out    = (float*)d_out;
    int*         flags  = (int*)d_ws;
    float*       wsv    = (float*)((char*)d_ws + WS_VEC_OFF);
    hipMemsetAsync(d_ws, 0, WS_VEC_OFF, stream);      // zero flags every call
    ctc_half_kernel<<<dim3(2 * Bc), dim3(192), 0, stream>>>(
        y_true, y_pred, out, wsv, flags);
}

// Round 17
// 25.305 us; speedup vs baseline: 1.8957x; 1.8957x over previous
//
#include <hip/hip_runtime.h>

// CTC batch cost, B=256 T=512 C=256 L=64 (S=129).
// R17 = R13 (reg-staging producers, 8-row groups, 32 raw s_barrier
// rendezvous, NS=48 ring, consumers wid0=fwd / wid1=bwd) with EIGHT
// producer waves (4 per direction, 2 rows of each group each; 10 waves
// total). Rationale: R13 (+4%) showed reg path > DMA path at 4 issuing
// waves/CU; m13's 6.3 TB/s ceiling was measured at ~8+ issuing waves/CU;
// R11's producer-doubling null was on the DMA path only. This fills the
// last untested cell of {path} x {issue-waves}. Producer cadence = R13's
// double-buffer with 2-load batches: vmcnt(2) steady (newer batch in
// flight), vmcnt(0) at tail. DP math: f64 linear domain, DPP shifts,
// log2-domain cut combine (absmax 0.0 in R6-R16).

constexpr int Bc = 256;
constexpr int Tc = 512;
constexpr int Cc = 256;
constexpr int Lc = 64;
constexpr int NS = 48;          // ring slots per direction = 6 groups x 8 rows

#define EPSF (1e-7f)
#define NEGF (-1e30f)

__device__ __forceinline__ float flog2(float x) {
    float r; asm("v_log_f32 %0, %1" : "=v"(r) : "v"(x)); return r;
}
__device__ __forceinline__ float fexp2(float x) {
    float r; asm("v_exp_f32 %0, %1" : "=v"(r) : "v"(x)); return r;
}
__device__ __forceinline__ float lse2(float a, float b) {
    float m = fmaxf(a, b);
    float d = fminf(a, b) - m;
    return m + flog2(1.f + fexp2(d));
}
// log2 of a positive double via exponent extraction + f32 mantissa log.
__device__ __forceinline__ float dlog2(double x) {
    if (!(x > 1e-300)) return NEGF;
    const int hb = __double2hiint(x);
    const int lb = __double2loint(x);
    const int e  = ((hb >> 20) & 0x7FF) - 1022;
    const double m = __hiloint2double((hb & 0x800FFFFF) | (1022 << 20), lb);
    return flog2((float)m) + (float)e;            // m in [0.5, 1)
}
// double wave shifts via paired 32-bit DPP; 'old' fills the boundary lane.
__device__ __forceinline__ double dpp_up1_d(double old, double src) {   // lane i <- i-1
    const int rl = __builtin_amdgcn_update_dpp(
        __double2loint(old), __double2loint(src), 0x138, 0xF, 0xF, false);
    const int rh = __builtin_amdgcn_update_dpp(
        __double2hiint(old), __double2hiint(src), 0x138, 0xF, 0xF, false);
    return __hiloint2double(rh, rl);
}
__device__ __forceinline__ double dpp_dn1_d(double old, double src) {   // lane i <- i+1
    const int rl = __builtin_amdgcn_update_dpp(
        __double2loint(old), __double2loint(src), 0x130, 0xF, 0xF, false);
    const int rh = __builtin_amdgcn_update_dpp(
        __double2hiint(old), __double2hiint(src), 0x130, 0xF, 0xF, false);
    return __hiloint2double(rh, rl);
}

__global__ __launch_bounds__(640, 1) void ctc_fb_kernel(
        const int* __restrict__ y_true,
        const float* __restrict__ y_pred,
        float* __restrict__ out)
{
    const int b    = blockIdx.x;
    const int lane = threadIdx.x & 63;
    const int wid  = threadIdx.x >> 6;

    __shared__ float ring[2][NS][Cc];       // 96 KB
    __shared__ float Cl[64], Ch[64];
    __shared__ float CexS;

    const float* __restrict__ bbase = y_pred + (size_t)b * Tc * Cc;

    double lo = 0.0, hi = 0.0, ex = 0.0;

    if (wid >= 2) {
        // -------- producer waves: pid = wid-2; dir = pid&1; q = pid>>1 -----
        const int pid = wid - 2;
        const int dir = pid & 1;
        const int q   = pid >> 1;            // quarter: rows 8g+2q, 8g+2q+1
        const float* __restrict__ g0 =
            dir ? (bbase + (size_t)(Tc - 1) * Cc + lane * 4)
                : (bbase + lane * 4);
        const ptrdiff_t stp = dir ? -(ptrdiff_t)Cc : (ptrdiff_t)Cc;

        float4 a0, a1, b0, b1;               // two named reg sets (rule #20)

#define GADDR(G, j) (g0 + stp * (8 * (G) + 2 * q + (j)))
#define LADDR(G, j) (&ring[dir][((G) % 6) * 8 + 2 * q + (j)][lane * 4])
#define PLOAD(v0, v1, G)                                           \
        v0 = *(const float4*)GADDR(G, 0);                          \
        v1 = *(const float4*)GADDR(G, 1);
#define PWRITE(v0, v1, G)                                          \
        *(float4*)LADDR(G, 0) = v0;                                \
        *(float4*)LADDR(G, 1) = v1;

        // prologue: load groups 0 (->A) and 1 (->B); write group 0.
        PLOAD(a0, a1, 0)
        PLOAD(b0, b1, 1)
        asm volatile("s_waitcnt vmcnt(2)" ::: "memory");   // group 0 regs ready
        PWRITE(a0, a1, 0)
        asm volatile("s_waitcnt lgkmcnt(0)" ::: "memory");

        for (int g = 0; g < 32; g += 2) {
            // ---- even iter g: issue g+2 -> A; retire+write g+1 from B ----
            asm volatile("" ::: "memory");
            __builtin_amdgcn_s_barrier();                  // #g (raw, no drain)
            asm volatile("" ::: "memory");
            if (g + 2 <= 31) { PLOAD(a0, a1, g + 2) }
            if (g <= 29) asm volatile("s_waitcnt vmcnt(2)" ::: "memory");
            else         asm volatile("s_waitcnt vmcnt(0)" ::: "memory");
            PWRITE(b0, b1, g + 1)
            asm volatile("s_waitcnt lgkmcnt(0)" ::: "memory");
            // ---- odd iter g+1: issue g+3 -> B; retire+write g+2 from A ----
            asm volatile("" ::: "memory");
            __builtin_amdgcn_s_barrier();                  // #g+1
            asm volatile("" ::: "memory");
            if (g + 3 <= 31) { PLOAD(b0, b1, g + 3) }
            if (g + 1 <= 29) asm volatile("s_waitcnt vmcnt(2)" ::: "memory");
            else             asm volatile("s_waitcnt vmcnt(0)" ::: "memory");
            if (g + 2 <= 31) {
                PWRITE(a0, a1, g + 2)
                asm volatile("s_waitcnt lgkmcnt(0)" ::: "memory");
            }
        }
#undef GADDR
#undef LADDR
#undef PLOAD
#undef PWRITE
    } else {
        // ---------------- consumer (DP) waves (R13/R9 form) ----------------
        const int lab  = y_true[b * Lc + lane];
        const int labp = __shfl_up(lab, 1);
        const int labn = __shfl_down(lab, 1);

        if (wid == 0) {
            // forward DP: steps/rows 0..255
            const bool allowF = (lane >= 1) && (lab != labp);
            auto stepF = [&](float pBf, float pLf) {
                const double pB = (double)pBf, pL = (double)pLf;
                const double prevHi = dpp_up1_d(0.0, hi);
                const double sk  = allowF ? prevHi : 0.0;
                const double nlo = (lo + prevHi) * pB;
                const double nhi = (hi + lo + sk) * pL;
                ex = (ex + hi) * pB;     // real only at lane 63 (127->128)
                hi = nhi; lo = nlo;
            };
            int sb = 0;
            for (int g = 0; g < 32; ++g) {
                asm volatile("" ::: "memory");
                __builtin_amdgcn_s_barrier();        // group g ready
                asm volatile("" ::: "memory");
#define RDF(j) const float cL##j = ring[0][sb + j][lab] + EPSF, \
                           cB##j = ring[0][sb + j][Cc - 1] + EPSF;
                RDF(0) RDF(1) RDF(2) RDF(3) RDF(4) RDF(5) RDF(6) RDF(7)
#undef RDF
                if (g == 0) {
                    lo = (lane == 0) ? (double)cB0 : 0.0;    // alpha0(0)
                    hi = (lane == 0) ? (double)cL0 : 0.0;    // alpha0(1)
                } else stepF(cB0, cL0);
                stepF(cB1, cL1); stepF(cB2, cL2); stepF(cB3, cL3);
                stepF(cB4, cL4); stepF(cB5, cL5); stepF(cB6, cL6);
                stepF(cB7, cL7);
                sb += 8; if (sb >= NS) sb = 0;
            }
        } else {
            // backward DP: local rows 0..255 <-> t = 511..256
            const bool allowB = (lane < 63) && (labn != lab);
            auto stepB = [&](float pBf, float pLf) {
                const double pB = (double)pBf, pL = (double)pLf;
                const double nlo_s = dpp_dn1_d(ex, lo);   // B(2l+2); l63 <- ex
                const double nhi_s = dpp_dn1_d(0.0, hi);  // B(2l+3); l63 <- 0
                const double sk = allowB ? nhi_s : 0.0;
                const double l2 = (lo + hi) * pB;
                const double h2 = (hi + nlo_s + sk) * pL;
                ex = ex * pB;
                lo = l2; hi = h2;
            };
            int sb = 0;
            for (int g = 0; g < 32; ++g) {
                asm volatile("" ::: "memory");
                __builtin_amdgcn_s_barrier();        // group g ready
                asm volatile("" ::: "memory");
#define RDB(j) const float cL##j = ring[1][sb + j][lab] + EPSF, \
                           cB##j = ring[1][sb + j][Cc - 1] + EPSF;
                RDB(0) RDB(1) RDB(2) RDB(3) RDB(4) RDB(5) RDB(6) RDB(7)
#undef RDB
                if (g == 0) {
                    ex = (double)cB0;                          // beta511(128)
                    hi = (lane == 63) ? (double)cL0 : 0.0;     // beta511(127)
                    lo = 0.0;
                } else stepB(cB0, cL0);
                stepB(cB1, cL1); stepB(cB2, cL2); stepB(cB3, cL3);
                stepB(cB4, cL4); stepB(cB5, cL5); stepB(cB6, cL6);
                stepB(cB7, cL7);
                sb += 8; if (sb >= NS) sb = 0;
            }
            // cut combine half-step: C(s) = B(s) + B(s+1) + allowB(s)*B(s+2),
            // stored log2-domain (R4 lesson: anti-aligned maxima).
            const double nlo_s = dpp_dn1_d(ex, lo);
            const double nhi_s = dpp_dn1_d(0.0, hi);
            const double sk = allowB ? nhi_s : 0.0;
            Cl[lane] = dlog2(lo + hi);
            Ch[lane] = dlog2(hi + nlo_s + sk);
            if (lane == 63) CexS = dlog2(ex);
        }
    }

    __syncthreads();

    if (wid == 0) {
        const float w1 = dlog2(lo) + Cl[lane];
        const float w2 = dlog2(hi) + Ch[lane];
        float w = lse2(w1, w2);
        if (lane == 63) w = lse2(w, dlog2(ex) + CexS);
        #pragma unroll
        for (int off = 32; off; off >>= 1) w = lse2(w, __shfl_xor(w, off));
        if (lane == 0)
            out[b] = -0.69314718055994530942f * w;     // ln2 * log2 -> ln
    }
}

extern "C" void kernel_launch(void* const* d_in, const int* in_sizes, int n_in,
                              void* d_out, int out_size, void* d_ws, size_t ws_size,
                              hipStream_t stream) {
    const int*   y_true = (const int*)d_in[0];
    const float* y_pred = (const float*)d_in[1];
    float*       out    = (float*)d_out;
    ctc_fb_kernel<<<dim3(Bc), dim3(640), 0, stream>>>(y_true, y_pred, out);
}